// Round 9
// baseline (284.549 us; speedup 1.0000x reference)
//
#include <hip/hip_runtime.h>
#include <hip/hip_bf16.h>

#define NB 8
#define NC 256
#define NCI 128
#define NPOS 6272   // 8*28*28
#define NM 1568     // 8*14*14
#define PTOT 50176  // 8*6272
#define LOG2E 1.44269504f

typedef __attribute__((ext_vector_type(8))) short bf16x8;
typedef __attribute__((ext_vector_type(4))) float f32x4;
#define MFMA(a,b,c) __builtin_amdgcn_mfma_f32_16x16x32_bf16((a),(b),(c),0,0,0)

__device__ __forceinline__ short f2bf(float f){
  union{float f; unsigned u;} v; v.f=f;
  unsigned r=(v.u + 0x7FFFu + ((v.u>>16)&1u))>>16;
  return (short)r;
}
__device__ __forceinline__ float bf2f(short s){
  union{unsigned u; float f;} v; v.u=((unsigned)(unsigned short)s)<<16; return v.f;
}
__device__ __forceinline__ float exp2v(float x){
  float r; asm("v_exp_f32 %0, %1" : "=v"(r) : "v"(x)); return r;
}
__device__ __forceinline__ unsigned cvtpk(float lo, float hi){
  unsigned r; asm("v_cvt_pk_bf16_f32 %0, %1, %2" : "=v"(r) : "v"(lo), "v"(hi)); return r;
}

// ---------------- weights fp32 -> bf16 (Ww gets hi/lo split) ----------------
__global__ void k_cvt_w(const float* __restrict__ Wt, const float* __restrict__ Wp,
                        const float* __restrict__ Wg, const float* __restrict__ Ww,
                        short* __restrict__ out){
  int i = blockIdx.x*256 + threadIdx.x;   // 131072 total
  if (i < 98304){
    const float* src; int off;
    if (i < 32768)      { src = Wt; off = i; }
    else if (i < 65536) { src = Wp; off = i-32768; }
    else                { src = Wg; off = i-65536; }
    out[i] = f2bf(src[off]);
  } else {
    float v = Ww[i-98304];
    short hi = f2bf(v);
    out[i] = hi;                                  // Ww_hi at [98304,131072)
    out[i+32768] = f2bf(v - bf2f(hi));            // Ww_lo at [131072,163840)
  }
}

// ---------------- x (c,pos) fp32 -> xT (pos,c) bf16 (vectorized b128 stores) ----------------
__global__ void k_transpose(const float* __restrict__ x, short* __restrict__ xT){
  __shared__ float tile[64][33];
  int b = blockIdx.z, c0 = blockIdx.y*64, p0 = blockIdx.x*32;
  int tx = threadIdx.x & 31, ty = threadIdx.x >> 5;   // ty in [0,8)
  const float* xb = x + (size_t)b*NC*NPOS;
  #pragma unroll
  for (int k=0;k<8;k++)
    tile[ty+8*k][tx] = xb[(size_t)(c0+ty+8*k)*NPOS + p0 + tx];
  __syncthreads();
  short* xTb = xT + (size_t)b*NPOS*NC;
  int pos = threadIdx.x >> 3, cg = threadIdx.x & 7;
  bf16x8 v;
  #pragma unroll
  for (int i=0;i<8;i++) v[i] = f2bf(tile[cg*8+i][pos]);
  *(bf16x8*)&xTb[(size_t)(p0+pos)*NC + c0 + cg*8] = v;
}

// ---------------- 3 projection convs fused: one pass over xT, widx loop inside ----------------
// theta (widx 0) is pre-scaled by log2(e) so attention can use raw v_exp_f32 (2^x).
__global__ __launch_bounds__(256) void k_conv(const short* __restrict__ xT, const short* __restrict__ Wbf,
                        const float* __restrict__ bt, const float* __restrict__ bp, const float* __restrict__ bg,
                        short* __restrict__ theta, short* __restrict__ phiF, short* __restrict__ gF){
  int b = blockIdx.z;
  int wv = threadIdx.x >> 6, lane = threadIdx.x & 63;
  int l16 = lane & 15, lg = lane >> 4;
  int p0 = blockIdx.x*128 + wv*32;
  int c0 = blockIdx.y*64;
  const short* xTb = xT + (size_t)b*NPOS*NC;
  bf16x8 a[2][8];
  #pragma unroll
  for (int ps=0;ps<2;ps++)
    #pragma unroll
    for (int ks=0;ks<8;ks++)
      a[ps][ks] = *(const bf16x8*)&xTb[(size_t)(p0+ps*16+l16)*NC + ks*32 + lg*8];
  for (int widx=0; widx<3; widx++){
    const short* Wb = Wbf + widx*32768;
    const float* bias = (widx==0) ? bt : ((widx==1) ? bp : bg);
    short* outp = (widx==0) ? theta : ((widx==1) ? phiF : gF);
    float osc = (widx==0) ? LOG2E : 1.0f;
    float bv[4];
    #pragma unroll
    for (int cs=0;cs<4;cs++) bv[cs] = bias[c0+cs*16+l16];
    f32x4 acc[2][4] = {};
    #pragma unroll
    for (int ks=0;ks<8;ks++)
      #pragma unroll
      for (int cs=0;cs<4;cs++){
        bf16x8 wf = *(const bf16x8*)&Wb[(c0+cs*16+l16)*NC + ks*32 + lg*8];
        acc[0][cs] = MFMA(a[0][ks], wf, acc[0][cs]);
        acc[1][cs] = MFMA(a[1][ks], wf, acc[1][cs]);
      }
    short* ob = outp + (size_t)b*NPOS*NCI;
    #pragma unroll
    for (int ps=0;ps<2;ps++)
      #pragma unroll
      for (int cs=0;cs<4;cs++)
        #pragma unroll
        for (int j=0;j<4;j++){
          int pos = p0 + ps*16 + lg*4 + j;
          int co  = c0 + cs*16 + l16;
          ob[(size_t)pos*NCI + co] = f2bf((acc[ps][cs][j] + bv[cs])*osc);
        }
  }
}

// ---------------- (1,2,2) max-pool: phiF(pos,128)->phiP(M,128); gF(pos,128)->gP(128,M) ----------------
__global__ void k_pool(const short* __restrict__ phiF, const short* __restrict__ gF,
                       short* __restrict__ phiP, short* __restrict__ gP){
  __shared__ short gb[128][17];
  int b = blockIdx.y, m0 = blockIdx.x*16;
  int lm = threadIdx.x >> 4, cg = threadIdx.x & 15, ci0 = cg*8;
  int m = m0 + lm;
  int tt = m/196, r = m%196, h2 = r/14, w2 = r%14;
  int pbase = tt*784 + h2*56 + w2*2;
  const short* pF  = phiF + (size_t)b*NPOS*NCI;
  const short* gFb = gF   + (size_t)b*NPOS*NCI;
  float pb[8], gv[8];
  #pragma unroll
  for (int i=0;i<8;i++){ pb[i]=-1e30f; gv[i]=-1e30f; }
  #pragma unroll
  for (int dh=0;dh<2;dh++)
    #pragma unroll
    for (int dw=0;dw<2;dw++){
      int pos = pbase + dh*28 + dw;
      bf16x8 v = *(const bf16x8*)&pF[(size_t)pos*NCI+ci0];
      bf16x8 g = *(const bf16x8*)&gFb[(size_t)pos*NCI+ci0];
      #pragma unroll
      for (int i=0;i<8;i++){ pb[i]=fmaxf(pb[i],bf2f(v[i])); gv[i]=fmaxf(gv[i],bf2f(g[i])); }
    }
  bf16x8 po;
  #pragma unroll
  for (int i=0;i<8;i++) po[i]=f2bf(pb[i]);
  *(bf16x8*)&phiP[(size_t)b*NM*NCI + (size_t)m*NCI + ci0] = po;
  #pragma unroll
  for (int i=0;i<8;i++) gb[ci0+i][lm] = f2bf(gv[i]);
  __syncthreads();
  if (threadIdx.x < 128){
    int row = threadIdx.x;
    bf16x8 a, c;
    #pragma unroll
    for (int j=0;j<8;j++){ a[j]=gb[row][j]; c[j]=gb[row][8+j]; }
    short* dst = gP + (size_t)b*NCI*NM + (size_t)row*NM + m0;
    *(bf16x8*)&dst[0] = a;
    *(bf16x8*)&dst[8] = c;
  }
}

// ---------------- flash attention v8: 4 waves x 16 q, phi+g LDS-staged shared, dbuf ----------------
__global__ __launch_bounds__(256) void k_attn(const short* __restrict__ theta, const short* __restrict__ phiP,
                       const short* __restrict__ gP, short* __restrict__ yhi, short* __restrict__ ylo){
  __shared__ __align__(16) char tiles[2][16384];        // [buf][ phi 8KB | g 8KB ]
  __shared__ __align__(16) unsigned pbs[4][320];        // per-wave: 16 rows x 20 dw
  int t = threadIdx.x;
  int wv = t >> 6, lane = t & 63;
  int l16 = lane & 15, lg = lane >> 4;
  int b = blockIdx.x & 7, qt = blockIdx.x >> 3;         // batch on low bits -> XCD-local K/V
  int q0 = qt*64 + wv*16;
  const short* th = theta + (size_t)b*NPOS*NCI;
  const char* gph = (const char*)(phiP + (size_t)b*NM*NCI);
  const char* gpg = (const char*)(gP   + (size_t)b*NCI*NM);

  // ---- staging geometry (256 thr, 4 x 16B chunks each: 2 phi + 2 g) ----
  int pr0 = t >> 4, ps0 = t & 15;                       // phi rows pr0, pr0+16; slot ps0
  int gr0 = t >> 2, gs0 = t & 3;                        // g rows gr0, gr0+64; chunk gs0
  int lw_p0 = pr0*256      + ((ps0 ^ (pr0 & 7)) << 4);
  int lw_p1 = (pr0+16)*256 + ((ps0 ^ (pr0 & 7)) << 4);
  int lw_g0 = 8192 + gr0*64      + ((gs0 ^ (gr0 & 3)) << 4);
  int lw_g1 = 8192 + (gr0+64)*64 + ((gs0 ^ (gr0 & 3)) << 4);
  size_t go_p0 = (size_t)pr0*256      + ps0*16;
  size_t go_p1 = (size_t)(pr0+16)*256 + ps0*16;
  size_t go_g0 = (size_t)gr0*(NM*2)      + gs0*16;
  size_t go_g1 = (size_t)(gr0+64)*(NM*2) + gs0*16;

  // ---- fragment read offsets (swizzled) ----
  int rp[2][4];
  #pragma unroll
  for (int mi=0;mi<2;mi++)
    #pragma unroll
    for (int kc=0;kc<4;kc++)
      rp[mi][kc] = (mi*16+l16)*256 + (((kc*4+lg) ^ (l16 & 7)) << 4);
  int rg[8];
  #pragma unroll
  for (int ct=0;ct<8;ct++)
    rg[ct] = 8192 + (ct*16+l16)*64 + ((lg ^ (l16 & 3)) << 4);

  // ---- P redistribution constants ----
  int lgs01 = (2*lg) & 3, lgs23 = (2*lg+1) & 3;
  int mi2 = (lg >> 1) * 2;
  int rbase = l16*20;

  // ---- Q fragments (B-operand of swapped QK): rows q0+l16 ----
  bf16x8 qf[4];
  #pragma unroll
  for (int kc=0;kc<4;kc++)
    qf[kc] = *(const bf16x8*)&th[(size_t)(q0+l16)*NCI + kc*32 + lg*8];
  f32x4 acc[8] = {};
  float lsum = 0.f;

  // ---- prologue: stage tile 0 ----
  {
    uint4 a0 = *(const uint4*)(gph + go_p0);
    uint4 a1 = *(const uint4*)(gph + go_p1);
    uint4 a2 = *(const uint4*)(gpg + go_g0);
    uint4 a3 = *(const uint4*)(gpg + go_g1);
    *(uint4*)(tiles[0] + lw_p0) = a0;
    *(uint4*)(tiles[0] + lw_p1) = a1;
    *(uint4*)(tiles[0] + lw_g0) = a2;
    *(uint4*)(tiles[0] + lw_g1) = a3;
  }
  __syncthreads();

  int cur = 0;
  for (int ms=0; ms<49; ms++){
    // issue next tile's global loads (consumed by LDS write after compute)
    uint4 a0, a1, a2, a3;
    if (ms < 48){
      size_t pb_ = (size_t)(ms+1)*8192;
      size_t gb_ = (size_t)(ms+1)*64;
      a0 = *(const uint4*)(gph + pb_ + go_p0);
      a1 = *(const uint4*)(gph + pb_ + go_p1);
      a2 = *(const uint4*)(gpg + gb_ + go_g0);
      a3 = *(const uint4*)(gpg + gb_ + go_g1);
    }
    const char* L = tiles[cur];
    bf16x8 pf[2][4];
    #pragma unroll
    for (int mi=0;mi<2;mi++)
      #pragma unroll
      for (int kc=0;kc<4;kc++)
        pf[mi][kc] = *(const bf16x8*)(L + rp[mi][kc]);
    // swapped QK: S(row=m, col=q)
    f32x4 s[2] = {};
    __builtin_amdgcn_s_setprio(1);
    #pragma unroll
    for (int mi=0;mi<2;mi++)
      #pragma unroll
      for (int kc=0;kc<4;kc++)
        s[mi] = MFMA(pf[mi][kc], qf[kc], s[mi]);
    __builtin_amdgcn_s_setprio(0);
    bf16x8 gf[8];
    #pragma unroll
    for (int ct=0;ct<8;ct++)
      gf[ct] = *(const bf16x8*)(L + rg[ct]);
    // softmax numerators: theta pre-scaled by log2e -> raw v_exp_f32
    {
      float e0=exp2v(s[0][0]), e1=exp2v(s[0][1]), e2=exp2v(s[0][2]), e3=exp2v(s[0][3]);
      float e4=exp2v(s[1][0]), e5=exp2v(s[1][1]), e6=exp2v(s[1][2]), e7=exp2v(s[1][3]);
      lsum += (e0+e1)+(e2+e3)+(e4+e5)+(e6+e7);
      uint4 pk;
      pk.x = cvtpk(e0,e1); pk.y = cvtpk(e2,e3); pk.z = cvtpk(e4,e5); pk.w = cvtpk(e6,e7);
      *(uint4*)&pbs[wv][rbase + lg*4] = pk;
    }
    union { unsigned u[4]; bf16x8 v; } pbv;
    pbv.u[0] = pbs[wv][rbase + lgs01*4 + mi2 + 0];
    pbv.u[1] = pbs[wv][rbase + lgs01*4 + mi2 + 1];
    pbv.u[2] = pbs[wv][rbase + lgs23*4 + mi2 + 0];
    pbv.u[3] = pbs[wv][rbase + lgs23*4 + mi2 + 1];
    // PV: yT(ci, q) += g(ci,m) . P(m,q)
    __builtin_amdgcn_s_setprio(1);
    #pragma unroll
    for (int ct=0;ct<8;ct++)
      acc[ct] = MFMA(gf[ct], pbv.v, acc[ct]);
    __builtin_amdgcn_s_setprio(0);
    // write next tile into alternate buffer
    if (ms < 48){
      char* D = tiles[cur^1];
      *(uint4*)(D + lw_p0) = a0;
      *(uint4*)(D + lw_p1) = a1;
      *(uint4*)(D + lw_g0) = a2;
      *(uint4*)(D + lw_g1) = a3;
    }
    __syncthreads();
    cur ^= 1;
  }

  // denominator: lane's q = l16; sum partials across lg groups
  short* ybh = yhi + (size_t)b*NPOS*NCI;
  short* ybl = ylo + (size_t)b*NPOS*NCI;
  {
    float v = lsum;
    v += __shfl_xor(v, 16); v += __shfl_xor(v, 32);
    float inv = 1.f / v;
    #pragma unroll
    for (int ct=0;ct<8;ct++){
      size_t idx = (size_t)(q0+l16)*NCI + ct*16 + lg*4;
      ushort4 h4, l4;
      #pragma unroll
      for (int j=0;j<4;j++){
        float val = acc[ct][j]*inv;
        short hi = f2bf(val);
        ((unsigned short*)&h4)[j] = (unsigned short)hi;
        ((unsigned short*)&l4)[j] = (unsigned short)f2bf(val - bf2f(hi));
      }
      *(ushort4*)&ybh[idx] = h4;
      *(ushort4*)&ybl[idx] = l4;
    }
  }
}

// ---------------- Ww GEMM (hi/lo) + per-channel partials; y read ONCE (cot loop inside) ----------------
// grid (49, 8); block 256; wave = 32 pos; partial slot per wave.
__global__ __launch_bounds__(256) void k_stats(const short* __restrict__ Wwbf, const short* __restrict__ yhi,
                        const short* __restrict__ ylo, const float* __restrict__ bw,
                        float* __restrict__ sum_part, float* __restrict__ sq_part){
  int wv = threadIdx.x>>6, lane = threadIdx.x&63;
  int l16 = lane&15, lg = lane>>4;
  int b = blockIdx.y;
  int p0 = blockIdx.x*128 + wv*32;
  int slot = (b*49 + blockIdx.x)*4 + wv;           // [0,1568)
  const short* ybh = yhi + (size_t)b*NPOS*NCI;
  const short* ybl = ylo + (size_t)b*NPOS*NCI;
  const short* Whi = Wwbf;
  const short* Wlo = Wwbf + 32768;
  bf16x8 bh[2][4], bl[2][4];
  #pragma unroll
  for (int ps=0;ps<2;ps++)
    #pragma unroll
    for (int ks=0;ks<4;ks++){
      size_t off = (size_t)(p0+ps*16+l16)*NCI + ks*32 + lg*8;
      bh[ps][ks] = *(const bf16x8*)&ybh[off];
      bl[ps][ks] = *(const bf16x8*)&ybl[off];
    }
  for (int cot=0; cot<16; cot++){
    bf16x8 ahi[4], alo[4];
    #pragma unroll
    for (int ks=0;ks<4;ks++){
      ahi[ks] = *(const bf16x8*)&Whi[(cot*16+l16)*NCI + ks*32 + lg*8];
      alo[ks] = *(const bf16x8*)&Wlo[(cot*16+l16)*NCI + ks*32 + lg*8];
    }
    f32x4 a0 = {}, a1 = {};
    #pragma unroll
    for (int ks=0;ks<4;ks++){
      a0 = MFMA(ahi[ks], bh[0][ks], a0);
      a0 = MFMA(ahi[ks], bl[0][ks], a0);
      a0 = MFMA(alo[ks], bh[0][ks], a0);
      a1 = MFMA(ahi[ks], bh[1][ks], a1);
      a1 = MFMA(ahi[ks], bl[1][ks], a1);
      a1 = MFMA(alo[ks], bh[1][ks], a1);
    }
    #pragma unroll
    for (int j=0;j<4;j++){
      int ch = cot*16 + lg*4 + j;
      float bwv = bw[ch];
      float v0 = a0[j] + bwv, v1 = a1[j] + bwv;
      float s = v0 + v1, q = v0*v0 + v1*v1;
      s += __shfl_xor(s,1); s += __shfl_xor(s,2); s += __shfl_xor(s,4); s += __shfl_xor(s,8);
      q += __shfl_xor(q,1); q += __shfl_xor(q,2); q += __shfl_xor(q,4); q += __shfl_xor(q,8);
      if (l16==0){
        sum_part[ch*1568 + slot] = s;
        sq_part [ch*1568 + slot] = q;
      }
    }
  }
}

__global__ void k_finstats(const float* __restrict__ sum_part, const float* __restrict__ sq_part,
                           const float* __restrict__ gamma, const float* __restrict__ beta,
                           float* __restrict__ scale, float* __restrict__ shift){
  __shared__ float r[4][2];
  int c = blockIdx.x;
  int t = threadIdx.x, wv = t>>6;
  float s=0.f, q=0.f;
  for (int k=t; k<1568; k+=256){ s += sum_part[c*1568+k]; q += sq_part[c*1568+k]; }
  #pragma unroll
  for (int off=1; off<64; off<<=1){ s += __shfl_xor(s,off); q += __shfl_xor(q,off); }
  if ((t&63)==0){ r[wv][0]=s; r[wv][1]=q; }
  __syncthreads();
  if (t==0){
    s = r[0][0]+r[1][0]+r[2][0]+r[3][0];
    q = r[0][1]+r[1][1]+r[2][1]+r[3][1];
    float mean = s*(1.f/PTOT);
    float var  = fmaxf(q*(1.f/PTOT) - mean*mean, 0.f);
    float rs = rsqrtf(var + 1e-5f);
    float sc = gamma[c]*rs;
    scale[c]=sc; shift[c]=beta[c]-mean*sc;
  }
}

// ---------------- Ww GEMM (hi/lo) + BN + residual; y read ONCE (cot loop inside) ----------------
__global__ __launch_bounds__(256) void k_out(const short* __restrict__ Wwbf, const short* __restrict__ yhi,
                      const short* __restrict__ ylo, const float* __restrict__ bw,
                      const float* __restrict__ scale, const float* __restrict__ shift,
                      const float* __restrict__ x, float* __restrict__ out){
  int wv = threadIdx.x>>6, lane = threadIdx.x&63;
  int l16 = lane&15, lg = lane>>4;
  int b = blockIdx.y;
  int p0 = blockIdx.x*128 + wv*32;
  const short* ybh = yhi + (size_t)b*NPOS*NCI;
  const short* ybl = ylo + (size_t)b*NPOS*NCI;
  const short* Whi = Wwbf;
  const short* Wlo = Wwbf + 32768;
  bf16x8 bh[2][4], bl[2][4];
  #pragma unroll
  for (int ps=0;ps<2;ps++)
    #pragma unroll
    for (int ks=0;ks<4;ks++){
      size_t off = (size_t)(p0+ps*16+l16)*NCI + ks*32 + lg*8;
      bh[ps][ks] = *(const bf16x8*)&ybh[off];
      bl[ps][ks] = *(const bf16x8*)&ybl[off];
    }
  for (int cot=0; cot<16; cot++){
    bf16x8 ahi[4], alo[4];
    #pragma unroll
    for (int ks=0;ks<4;ks++){
      ahi[ks] = *(const bf16x8*)&Whi[(cot*16+l16)*NCI + ks*32 + lg*8];
      alo[ks] = *(const bf16x8*)&Wlo[(cot*16+l16)*NCI + ks*32 + lg*8];
    }
    f32x4 a0 = {}, a1 = {};
    #pragma unroll
    for (int ks=0;ks<4;ks++){
      a0 = MFMA(ahi[ks], bh[0][ks], a0);
      a0 = MFMA(ahi[ks], bl[0][ks], a0);
      a0 = MFMA(alo[ks], bh[0][ks], a0);
      a1 = MFMA(ahi[ks], bh[1][ks], a1);
      a1 = MFMA(ahi[ks], bl[1][ks], a1);
      a1 = MFMA(alo[ks], bh[1][ks], a1);
    }
    #pragma unroll
    for (int j=0;j<4;j++){
      int ch = cot*16 + lg*4 + j;
      float bwv = bw[ch], scv = scale[ch], shv = shift[ch];
      size_t base = ((size_t)b*NC + ch)*NPOS;
      size_t i0 = base + p0 + l16;
      size_t i1 = base + p0 + 16 + l16;
      float v0 = a0[j] + bwv, v1 = a1[j] + bwv;
      out[i0] = v0*scv + shv + x[i0];
      out[i1] = v1*scv + shv + x[i1];
    }
  }
}

extern "C" void kernel_launch(void* const* d_in, const int* in_sizes, int n_in,
                              void* d_out, int out_size, void* d_ws, size_t ws_size,
                              hipStream_t stream){
  const float* x     = (const float*)d_in[0];
  const float* Wg    = (const float*)d_in[1];
  const float* bg    = (const float*)d_in[2];
  const float* Wt    = (const float*)d_in[3];
  const float* bt    = (const float*)d_in[4];
  const float* Wp    = (const float*)d_in[5];
  const float* bp    = (const float*)d_in[6];
  const float* Ww    = (const float*)d_in[7];
  const float* bw    = (const float*)d_in[8];
  const float* gamma = (const float*)d_in[9];
  const float* beta  = (const float*)d_in[10];
  float* out = (float*)d_out;

  char* w = (char*)d_ws;
  short* Wbf   = (short*)w;                       // 163840 el -> 327680 B (Wt,Wp,Wg,Ww_hi,Ww_lo)
  short* xT    = (short*)(w + 327680);            // 25,690,112 B  (reused as y_hi)
  short* theta = (short*)(w + 327680 + 25690112);
  short* phiF  = (short*)((char*)theta + 12845056);   // reused as y_lo
  short* gF    = (short*)((char*)phiF  + 12845056);   // reused for BN partials
  short* phiP  = (short*)((char*)gF    + 12845056);
  short* gP    = (short*)((char*)phiP  + 3211264);
  float* sum_part = (float*)gF;                        // 256*1568*4 = 1,605,632 B
  float* sq_part  = (float*)((char*)gF + 1605632);
  float* scale    = (float*)((char*)gF + 3211264);
  float* shift    = (float*)((char*)gF + 3212288);
  short* yhi = xT;                                // alias: xT dead after k_conv
  short* ylo = phiF;                              // alias: phiF dead after k_pool

  k_cvt_w<<<dim3(512),256,0,stream>>>(Wt,Wp,Wg,Ww,Wbf);
  k_transpose<<<dim3(196,4,8),256,0,stream>>>(x,xT);
  k_conv<<<dim3(49,2,8),256,0,stream>>>(xT,Wbf,bt,bp,bg,theta,phiF,gF);
  k_pool<<<dim3(98,8),256,0,stream>>>(phiF,gF,phiP,gP);
  k_attn<<<dim3(784),256,0,stream>>>(theta,phiP,gP,yhi,ylo);
  const short* Wwbf = Wbf + 98304;
  k_stats<<<dim3(49,8),256,0,stream>>>(Wwbf,yhi,ylo,bw,sum_part,sq_part);
  k_finstats<<<dim3(256),256,0,stream>>>(sum_part,sq_part,gamma,beta,scale,shift);
  k_out<<<dim3(49,8),256,0,stream>>>(Wwbf,yhi,ylo,bw,scale,shift,x,out);
}

// Round 10
// 250.231 us; speedup vs baseline: 1.1371x; 1.1371x over previous
//
#include <hip/hip_runtime.h>
#include <hip/hip_bf16.h>

#define NB 8
#define NC 256
#define NCI 128
#define NPOS 6272   // 8*28*28
#define NM 1568     // 8*14*14
#define PTOT 50176  // 8*6272
#define LOG2E 1.44269504f

typedef __attribute__((ext_vector_type(8))) short bf16x8;
typedef __attribute__((ext_vector_type(4))) float f32x4;
#define MFMA(a,b,c) __builtin_amdgcn_mfma_f32_16x16x32_bf16((a),(b),(c),0,0,0)

__device__ __forceinline__ short f2bf(float f){
  union{float f; unsigned u;} v; v.f=f;
  unsigned r=(v.u + 0x7FFFu + ((v.u>>16)&1u))>>16;
  return (short)r;
}
__device__ __forceinline__ float bf2f(short s){
  union{unsigned u; float f;} v; v.u=((unsigned)(unsigned short)s)<<16; return v.f;
}
__device__ __forceinline__ float exp2v(float x){
  float r; asm("v_exp_f32 %0, %1" : "=v"(r) : "v"(x)); return r;
}
__device__ __forceinline__ unsigned cvtpk(float lo, float hi){
  unsigned r; asm("v_cvt_pk_bf16_f32 %0, %1, %2" : "=v"(r) : "v"(lo), "v"(hi)); return r;
}

// ---------------- weights fp32 -> bf16 (Ww gets hi/lo split) ----------------
__global__ void k_cvt_w(const float* __restrict__ Wt, const float* __restrict__ Wp,
                        const float* __restrict__ Wg, const float* __restrict__ Ww,
                        short* __restrict__ out){
  int i = blockIdx.x*256 + threadIdx.x;   // 131072 total
  if (i < 98304){
    const float* src; int off;
    if (i < 32768)      { src = Wt; off = i; }
    else if (i < 65536) { src = Wp; off = i-32768; }
    else                { src = Wg; off = i-65536; }
    out[i] = f2bf(src[off]);
  } else {
    float v = Ww[i-98304];
    short hi = f2bf(v);
    out[i] = hi;                                  // Ww_hi at [98304,131072)
    out[i+32768] = f2bf(v - bf2f(hi));            // Ww_lo at [131072,163840)
  }
}

// ---------------- fused transpose + 3 projection convs ----------------
// grid (196, 8); block 256 (= NC channels). Per block: 32 positions.
// thread t loads x[b, t, p0:p0+32] (128B coalesced), transposes into swizzled LDS [pos][c] bf16,
// then wave wv computes out-channels wv*32..wv*32+31 for all 3 convs (A-frags loaded once).
// theta (widx 0) pre-scaled by log2(e) so attention uses raw v_exp_f32.
__global__ __launch_bounds__(256) void k_tconv(const float* __restrict__ x, const short* __restrict__ Wbf,
                        const float* __restrict__ bt, const float* __restrict__ bp, const float* __restrict__ bg,
                        short* __restrict__ theta, short* __restrict__ phiF, short* __restrict__ gF){
  __shared__ short xt[32*256];   // [pos][c], 16B-granule swizzle: g' = (c>>3) ^ (pos&7)
  int t = threadIdx.x;
  int wv = t >> 6, lane = t & 63;
  int l16 = lane & 15, lg = lane >> 4;
  int b = blockIdx.y, p0 = blockIdx.x*32;
  {
    const float* xr = x + ((size_t)b*NC + t)*NPOS + p0;
    union { float4 q[8]; float f[32]; } u;
    #pragma unroll
    for (int k=0;k<8;k++) u.q[k] = *(const float4*)(xr + k*4);
    int g0 = t >> 3, cb = t & 7;
    #pragma unroll
    for (int pos=0; pos<32; pos++)
      xt[pos*256 + ((g0 ^ (pos&7))<<3) + cb] = f2bf(u.f[pos]);
  }
  __syncthreads();
  // A-fragments (reused across the 3 convs)
  bf16x8 a[2][8];
  #pragma unroll
  for (int ms=0;ms<2;ms++)
    #pragma unroll
    for (int ks=0;ks<8;ks++){
      int row = ms*16 + l16;
      a[ms][ks] = *(const bf16x8*)&xt[row*256 + (((ks*4+lg) ^ (row&7))<<3)];
    }
  int n0 = wv*32;
  for (int widx=0; widx<3; widx++){
    const short* Wb = Wbf + widx*32768;
    const float* bias = (widx==0) ? bt : ((widx==1) ? bp : bg);
    short* outp = (widx==0) ? theta : ((widx==1) ? phiF : gF);
    float osc = (widx==0) ? LOG2E : 1.0f;
    float bv[2];
    bv[0] = bias[n0+l16]; bv[1] = bias[n0+16+l16];
    f32x4 acc[2][2] = {};
    #pragma unroll
    for (int ks=0;ks<8;ks++)
      #pragma unroll
      for (int cs=0;cs<2;cs++){
        bf16x8 wf = *(const bf16x8*)&Wb[(n0+cs*16+l16)*NC + ks*32 + lg*8];
        acc[0][cs] = MFMA(a[0][ks], wf, acc[0][cs]);
        acc[1][cs] = MFMA(a[1][ks], wf, acc[1][cs]);
      }
    short* ob = outp + (size_t)b*NPOS*NCI;
    #pragma unroll
    for (int ms=0;ms<2;ms++)
      #pragma unroll
      for (int cs=0;cs<2;cs++)
        #pragma unroll
        for (int j=0;j<4;j++){
          int pos = p0 + ms*16 + lg*4 + j;
          int co  = n0 + cs*16 + l16;
          ob[(size_t)pos*NCI + co] = f2bf((acc[ms][cs][j] + bv[cs])*osc);
        }
  }
}

// ---------------- (1,2,2) max-pool: phiF(pos,128)->phiP(M,128); gF(pos,128)->gP(128,M) ----------------
__global__ void k_pool(const short* __restrict__ phiF, const short* __restrict__ gF,
                       short* __restrict__ phiP, short* __restrict__ gP){
  __shared__ short gb[128][17];
  int b = blockIdx.y, m0 = blockIdx.x*16;
  int lm = threadIdx.x >> 4, cg = threadIdx.x & 15, ci0 = cg*8;
  int m = m0 + lm;
  int tt = m/196, r = m%196, h2 = r/14, w2 = r%14;
  int pbase = tt*784 + h2*56 + w2*2;
  const short* pF  = phiF + (size_t)b*NPOS*NCI;
  const short* gFb = gF   + (size_t)b*NPOS*NCI;
  float pb[8], gv[8];
  #pragma unroll
  for (int i=0;i<8;i++){ pb[i]=-1e30f; gv[i]=-1e30f; }
  #pragma unroll
  for (int dh=0;dh<2;dh++)
    #pragma unroll
    for (int dw=0;dw<2;dw++){
      int pos = pbase + dh*28 + dw;
      bf16x8 v = *(const bf16x8*)&pF[(size_t)pos*NCI+ci0];
      bf16x8 g = *(const bf16x8*)&gFb[(size_t)pos*NCI+ci0];
      #pragma unroll
      for (int i=0;i<8;i++){ pb[i]=fmaxf(pb[i],bf2f(v[i])); gv[i]=fmaxf(gv[i],bf2f(g[i])); }
    }
  bf16x8 po;
  #pragma unroll
  for (int i=0;i<8;i++) po[i]=f2bf(pb[i]);
  *(bf16x8*)&phiP[(size_t)b*NM*NCI + (size_t)m*NCI + ci0] = po;
  #pragma unroll
  for (int i=0;i<8;i++) gb[ci0+i][lm] = f2bf(gv[i]);
  __syncthreads();
  if (threadIdx.x < 128){
    int row = threadIdx.x;
    bf16x8 a, c;
    #pragma unroll
    for (int j=0;j<8;j++){ a[j]=gb[row][j]; c[j]=gb[row][8+j]; }
    short* dst = gP + (size_t)b*NCI*NM + (size_t)row*NM + m0;
    *(bf16x8*)&dst[0] = a;
    *(bf16x8*)&dst[8] = c;
  }
}

// ---------------- flash attention v5b: 2 waves x 32 q, phi+g LDS dbuf, exp2 + cvt_pk ----------------
__global__ __launch_bounds__(128,2) void k_attn(const short* __restrict__ theta, const short* __restrict__ phiP,
                       const short* __restrict__ gP, short* __restrict__ yhi, short* __restrict__ ylo){
  __shared__ __align__(16) char tiles[2][16384];        // [buf][ phi 8KB | g 8KB ]
  __shared__ __align__(16) unsigned pbs[2][2][320];     // [wave][qi][16 rows x 20 dw]
  int t = threadIdx.x;
  int wv = t >> 6, lane = t & 63;
  int l16 = lane & 15, lg = lane >> 4;
  int b = blockIdx.x & 7, qt = blockIdx.x >> 3;         // batch on low bits -> XCD-local K/V
  int q0 = qt*64 + wv*32;
  const short* th = theta + (size_t)b*NPOS*NCI;
  const char* gph = (const char*)(phiP + (size_t)b*NM*NCI);
  const char* gpg = (const char*)(gP   + (size_t)b*NCI*NM);

  // ---- staging geometry: 128 threads stage 16 KB (8 x 16B chunks each) ----
  int pr = (t >> 4) & 7, ps = t & 15;                   // phi rows pr+8k, slot ps
  int gr = t >> 2, gs = t & 3;                          // g rows gr+32k, chunk gs
  int lw_p[4], lw_g[4]; size_t go_p[4], go_g[4];
  #pragma unroll
  for (int k=0;k<4;k++){
    lw_p[k] = (pr+8*k)*256 + ((ps ^ pr) << 4);
    go_p[k] = (size_t)(pr+8*k)*256 + ps*16;
    lw_g[k] = 8192 + (gr+32*k)*64 + ((gs ^ (gr & 3)) << 4);
    go_g[k] = (size_t)(gr+32*k)*(NM*2) + gs*16;
  }
  // ---- fragment read offsets (swizzled) ----
  int rp[2][4];
  #pragma unroll
  for (int mi=0;mi<2;mi++)
    #pragma unroll
    for (int kc=0;kc<4;kc++)
      rp[mi][kc] = (mi*16+l16)*256 + (((kc*4+lg) ^ (l16 & 7)) << 4);
  int rg[8];
  #pragma unroll
  for (int ct=0;ct<8;ct++)
    rg[ct] = 8192 + (ct*16+l16)*64 + ((lg ^ (l16 & 3)) << 4);

  // ---- P redistribution constants ----
  int lgs01 = (2*lg) & 3, lgs23 = (2*lg+1) & 3;
  int mi2 = (lg >> 1) * 2;
  int rbase = l16*20;

  // ---- Q fragments (B-operand of swapped QK): rows q0+qi*16+l16 ----
  bf16x8 qf[2][4];
  #pragma unroll
  for (int qi=0;qi<2;qi++)
    #pragma unroll
    for (int kc=0;kc<4;kc++)
      qf[qi][kc] = *(const bf16x8*)&th[(size_t)(q0+qi*16+l16)*NCI + kc*32 + lg*8];
  f32x4 acc[2][8] = {};
  float lsum[2] = {0.f, 0.f};

  // ---- prologue: stage tile 0 ----
  {
    uint4 A[8];
    #pragma unroll
    for (int k=0;k<4;k++){ A[k] = *(const uint4*)(gph + go_p[k]); A[4+k] = *(const uint4*)(gpg + go_g[k]); }
    #pragma unroll
    for (int k=0;k<4;k++){ *(uint4*)(tiles[0] + lw_p[k]) = A[k]; *(uint4*)(tiles[0] + lw_g[k]) = A[4+k]; }
  }
  __syncthreads();

  int cur = 0;
  for (int ms=0; ms<49; ms++){
    uint4 A[8];
    if (ms < 48){
      size_t pb_ = (size_t)(ms+1)*8192;
      size_t gb_ = (size_t)(ms+1)*64;
      #pragma unroll
      for (int k=0;k<4;k++){ A[k] = *(const uint4*)(gph + pb_ + go_p[k]); A[4+k] = *(const uint4*)(gpg + gb_ + go_g[k]); }
    }
    const char* L = tiles[cur];
    bf16x8 pf[2][4];
    #pragma unroll
    for (int mi=0;mi<2;mi++)
      #pragma unroll
      for (int kc=0;kc<4;kc++)
        pf[mi][kc] = *(const bf16x8*)(L + rp[mi][kc]);
    // swapped QK: S(row=m, col=q): s[qi][mi]
    f32x4 s[2][2] = {};
    __builtin_amdgcn_s_setprio(1);
    #pragma unroll
    for (int qi=0;qi<2;qi++)
      #pragma unroll
      for (int mi=0;mi<2;mi++)
        #pragma unroll
        for (int kc=0;kc<4;kc++)
          s[qi][mi] = MFMA(pf[mi][kc], qf[qi][kc], s[qi][mi]);
    __builtin_amdgcn_s_setprio(0);
    bf16x8 gf[8];
    #pragma unroll
    for (int ct=0;ct<8;ct++)
      gf[ct] = *(const bf16x8*)(L + rg[ct]);
    // softmax numerators: theta pre-scaled by log2e -> raw v_exp_f32; pack via v_cvt_pk_bf16_f32
    #pragma unroll
    for (int qi=0;qi<2;qi++){
      float e0=exp2v(s[qi][0][0]), e1=exp2v(s[qi][0][1]), e2=exp2v(s[qi][0][2]), e3=exp2v(s[qi][0][3]);
      float e4=exp2v(s[qi][1][0]), e5=exp2v(s[qi][1][1]), e6=exp2v(s[qi][1][2]), e7=exp2v(s[qi][1][3]);
      lsum[qi] += (e0+e1)+(e2+e3)+(e4+e5)+(e6+e7);
      uint4 pk;
      pk.x = cvtpk(e0,e1); pk.y = cvtpk(e2,e3); pk.z = cvtpk(e4,e5); pk.w = cvtpk(e6,e7);
      *(uint4*)&pbs[wv][qi][rbase + lg*4] = pk;
    }
    union { unsigned u[4]; bf16x8 v; } pbv[2];
    #pragma unroll
    for (int qi=0;qi<2;qi++){
      pbv[qi].u[0] = pbs[wv][qi][rbase + lgs01*4 + mi2 + 0];
      pbv[qi].u[1] = pbs[wv][qi][rbase + lgs01*4 + mi2 + 1];
      pbv[qi].u[2] = pbs[wv][qi][rbase + lgs23*4 + mi2 + 0];
      pbv[qi].u[3] = pbs[wv][qi][rbase + lgs23*4 + mi2 + 1];
    }
    // PV: yT(ci, q) += g(ci,m) . P(m,q)
    __builtin_amdgcn_s_setprio(1);
    #pragma unroll
    for (int ct=0;ct<8;ct++){
      acc[0][ct] = MFMA(gf[ct], pbv[0].v, acc[0][ct]);
      acc[1][ct] = MFMA(gf[ct], pbv[1].v, acc[1][ct]);
    }
    __builtin_amdgcn_s_setprio(0);
    if (ms < 48){
      char* D = tiles[cur^1];
      #pragma unroll
      for (int k=0;k<4;k++){ *(uint4*)(D + lw_p[k]) = A[k]; *(uint4*)(D + lw_g[k]) = A[4+k]; }
    }
    __syncthreads();
    cur ^= 1;
  }

  // denominator: lane's q = l16; sum partials across lg groups
  short* ybh = yhi + (size_t)b*NPOS*NCI;
  short* ybl = ylo + (size_t)b*NPOS*NCI;
  #pragma unroll
  for (int qi=0;qi<2;qi++){
    float v = lsum[qi];
    v += __shfl_xor(v, 16); v += __shfl_xor(v, 32);
    float inv = 1.f / v;
    #pragma unroll
    for (int ct=0;ct<8;ct++){
      size_t idx = (size_t)(q0+qi*16+l16)*NCI + ct*16 + lg*4;
      ushort4 h4, l4;
      #pragma unroll
      for (int j=0;j<4;j++){
        float val = acc[qi][ct][j]*inv;
        short hi = f2bf(val);
        ((unsigned short*)&h4)[j] = (unsigned short)hi;
        ((unsigned short*)&l4)[j] = (unsigned short)f2bf(val - bf2f(hi));
      }
      *(ushort4*)&ybh[idx] = h4;
      *(ushort4*)&ybl[idx] = l4;
    }
  }
}

// ---------------- Ww GEMM (hi/lo) + per-channel partials; y read ONCE (cot loop inside) ----------------
// grid (49, 8); block 256; wave = 32 pos; partial slot per wave.
__global__ __launch_bounds__(256) void k_stats(const short* __restrict__ Wwbf, const short* __restrict__ yhi,
                        const short* __restrict__ ylo, const float* __restrict__ bw,
                        float* __restrict__ sum_part, float* __restrict__ sq_part){
  int wv = threadIdx.x>>6, lane = threadIdx.x&63;
  int l16 = lane&15, lg = lane>>4;
  int b = blockIdx.y;
  int p0 = blockIdx.x*128 + wv*32;
  int slot = (b*49 + blockIdx.x)*4 + wv;           // [0,1568)
  const short* ybh = yhi + (size_t)b*NPOS*NCI;
  const short* ybl = ylo + (size_t)b*NPOS*NCI;
  const short* Whi = Wwbf;
  const short* Wlo = Wwbf + 32768;
  bf16x8 bh[2][4], bl[2][4];
  #pragma unroll
  for (int ps=0;ps<2;ps++)
    #pragma unroll
    for (int ks=0;ks<4;ks++){
      size_t off = (size_t)(p0+ps*16+l16)*NCI + ks*32 + lg*8;
      bh[ps][ks] = *(const bf16x8*)&ybh[off];
      bl[ps][ks] = *(const bf16x8*)&ybl[off];
    }
  for (int cot=0; cot<16; cot++){
    bf16x8 ahi[4], alo[4];
    #pragma unroll
    for (int ks=0;ks<4;ks++){
      ahi[ks] = *(const bf16x8*)&Whi[(cot*16+l16)*NCI + ks*32 + lg*8];
      alo[ks] = *(const bf16x8*)&Wlo[(cot*16+l16)*NCI + ks*32 + lg*8];
    }
    f32x4 a0 = {}, a1 = {};
    #pragma unroll
    for (int ks=0;ks<4;ks++){
      a0 = MFMA(ahi[ks], bh[0][ks], a0);
      a0 = MFMA(ahi[ks], bl[0][ks], a0);
      a0 = MFMA(alo[ks], bh[0][ks], a0);
      a1 = MFMA(ahi[ks], bh[1][ks], a1);
      a1 = MFMA(ahi[ks], bl[1][ks], a1);
      a1 = MFMA(alo[ks], bh[1][ks], a1);
    }
    #pragma unroll
    for (int j=0;j<4;j++){
      int ch = cot*16 + lg*4 + j;
      float bwv = bw[ch];
      float v0 = a0[j] + bwv, v1 = a1[j] + bwv;
      float s = v0 + v1, q = v0*v0 + v1*v1;
      s += __shfl_xor(s,1); s += __shfl_xor(s,2); s += __shfl_xor(s,4); s += __shfl_xor(s,8);
      q += __shfl_xor(q,1); q += __shfl_xor(q,2); q += __shfl_xor(q,4); q += __shfl_xor(q,8);
      if (l16==0){
        sum_part[ch*1568 + slot] = s;
        sq_part [ch*1568 + slot] = q;
      }
    }
  }
}

__global__ void k_finstats(const float* __restrict__ sum_part, const float* __restrict__ sq_part,
                           const float* __restrict__ gamma, const float* __restrict__ beta,
                           float* __restrict__ scale, float* __restrict__ shift){
  __shared__ float r[4][2];
  int c = blockIdx.x;
  int t = threadIdx.x, wv = t>>6;
  float s=0.f, q=0.f;
  for (int k=t; k<1568; k+=256){ s += sum_part[c*1568+k]; q += sq_part[c*1568+k]; }
  #pragma unroll
  for (int off=1; off<64; off<<=1){ s += __shfl_xor(s,off); q += __shfl_xor(q,off); }
  if ((t&63)==0){ r[wv][0]=s; r[wv][1]=q; }
  __syncthreads();
  if (t==0){
    s = r[0][0]+r[1][0]+r[2][0]+r[3][0];
    q = r[0][1]+r[1][1]+r[2][1]+r[3][1];
    float mean = s*(1.f/PTOT);
    float var  = fmaxf(q*(1.f/PTOT) - mean*mean, 0.f);
    float rs = rsqrtf(var + 1e-5f);
    float sc = gamma[c]*rs;
    scale[c]=sc; shift[c]=beta[c]-mean*sc;
  }
}

// ---------------- Ww GEMM (hi/lo) + BN + residual; y read ONCE (cot loop inside) ----------------
__global__ __launch_bounds__(256) void k_out(const short* __restrict__ Wwbf, const short* __restrict__ yhi,
                      const short* __restrict__ ylo, const float* __restrict__ bw,
                      const float* __restrict__ scale, const float* __restrict__ shift,
                      const float* __restrict__ x, float* __restrict__ out){
  int wv = threadIdx.x>>6, lane = threadIdx.x&63;
  int l16 = lane&15, lg = lane>>4;
  int b = blockIdx.y;
  int p0 = blockIdx.x*128 + wv*32;
  const short* ybh = yhi + (size_t)b*NPOS*NCI;
  const short* ybl = ylo + (size_t)b*NPOS*NCI;
  const short* Whi = Wwbf;
  const short* Wlo = Wwbf + 32768;
  bf16x8 bh[2][4], bl[2][4];
  #pragma unroll
  for (int ps=0;ps<2;ps++)
    #pragma unroll
    for (int ks=0;ks<4;ks++){
      size_t off = (size_t)(p0+ps*16+l16)*NCI + ks*32 + lg*8;
      bh[ps][ks] = *(const bf16x8*)&ybh[off];
      bl[ps][ks] = *(const bf16x8*)&ybl[off];
    }
  for (int cot=0; cot<16; cot++){
    bf16x8 ahi[4], alo[4];
    #pragma unroll
    for (int ks=0;ks<4;ks++){
      ahi[ks] = *(const bf16x8*)&Whi[(cot*16+l16)*NCI + ks*32 + lg*8];
      alo[ks] = *(const bf16x8*)&Wlo[(cot*16+l16)*NCI + ks*32 + lg*8];
    }
    f32x4 a0 = {}, a1 = {};
    #pragma unroll
    for (int ks=0;ks<4;ks++){
      a0 = MFMA(ahi[ks], bh[0][ks], a0);
      a0 = MFMA(ahi[ks], bl[0][ks], a0);
      a0 = MFMA(alo[ks], bh[0][ks], a0);
      a1 = MFMA(ahi[ks], bh[1][ks], a1);
      a1 = MFMA(ahi[ks], bl[1][ks], a1);
      a1 = MFMA(alo[ks], bh[1][ks], a1);
    }
    #pragma unroll
    for (int j=0;j<4;j++){
      int ch = cot*16 + lg*4 + j;
      float bwv = bw[ch], scv = scale[ch], shv = shift[ch];
      size_t base = ((size_t)b*NC + ch)*NPOS;
      size_t i0 = base + p0 + l16;
      size_t i1 = base + p0 + 16 + l16;
      float v0 = a0[j] + bwv, v1 = a1[j] + bwv;
      out[i0] = v0*scv + shv + x[i0];
      out[i1] = v1*scv + shv + x[i1];
    }
  }
}

extern "C" void kernel_launch(void* const* d_in, const int* in_sizes, int n_in,
                              void* d_out, int out_size, void* d_ws, size_t ws_size,
                              hipStream_t stream){
  const float* x     = (const float*)d_in[0];
  const float* Wg    = (const float*)d_in[1];
  const float* bg    = (const float*)d_in[2];
  const float* Wt    = (const float*)d_in[3];
  const float* bt    = (const float*)d_in[4];
  const float* Wp    = (const float*)d_in[5];
  const float* bp    = (const float*)d_in[6];
  const float* Ww    = (const float*)d_in[7];
  const float* bw    = (const float*)d_in[8];
  const float* gamma = (const float*)d_in[9];
  const float* beta  = (const float*)d_in[10];
  float* out = (float*)d_out;

  char* w = (char*)d_ws;
  short* Wbf   = (short*)w;                       // 163840 el -> 327680 B (Wt,Wp,Wg,Ww_hi,Ww_lo)
  short* xT    = (short*)(w + 327680);            // region reused as y_hi
  short* theta = (short*)(w + 327680 + 25690112);
  short* phiF  = (short*)((char*)theta + 12845056);   // reused as y_lo
  short* gF    = (short*)((char*)phiF  + 12845056);   // reused for BN partials
  short* phiP  = (short*)((char*)gF    + 12845056);
  short* gP    = (short*)((char*)phiP  + 3211264);
  float* sum_part = (float*)gF;                        // 256*1568*4 = 1,605,632 B
  float* sq_part  = (float*)((char*)gF + 1605632);
  float* scale    = (float*)((char*)gF + 3211264);
  float* shift    = (float*)((char*)gF + 3212288);
  short* yhi = xT;
  short* ylo = phiF;                              // alias: phiF dead after k_pool

  k_cvt_w<<<dim3(512),256,0,stream>>>(Wt,Wp,Wg,Ww,Wbf);
  k_tconv<<<dim3(196,8),256,0,stream>>>(x,Wbf,bt,bp,bg,theta,phiF,gF);
  k_pool<<<dim3(98,8),256,0,stream>>>(phiF,gF,phiP,gP);
  k_attn<<<dim3(784),128,0,stream>>>(theta,phiP,gP,yhi,ylo);
  const short* Wwbf = Wbf + 98304;
  k_stats<<<dim3(49,8),256,0,stream>>>(Wwbf,yhi,ylo,bw,sum_part,sq_part);
  k_finstats<<<dim3(256),256,0,stream>>>(sum_part,sq_part,gamma,beta,scale,shift);
  k_out<<<dim3(49,8),256,0,stream>>>(Wwbf,yhi,ylo,bw,scale,shift,x,out);
}

// Round 11
// 197.990 us; speedup vs baseline: 1.4372x; 1.2639x over previous
//
#include <hip/hip_runtime.h>
#include <hip/hip_bf16.h>

#define NB 8
#define NC 256
#define NCI 128
#define NPOS 6272   // 8*28*28
#define NM 1568     // 8*14*14
#define PTOT 50176  // 8*6272
#define LOG2E 1.44269504f

typedef __attribute__((ext_vector_type(8))) short bf16x8;
typedef __attribute__((ext_vector_type(4))) float f32x4;
#define MFMA(a,b,c) __builtin_amdgcn_mfma_f32_16x16x32_bf16((a),(b),(c),0,0,0)

__device__ __forceinline__ short f2bf(float f){
  union{float f; unsigned u;} v; v.f=f;
  unsigned r=(v.u + 0x7FFFu + ((v.u>>16)&1u))>>16;
  return (short)r;
}
__device__ __forceinline__ float bf2f(short s){
  union{unsigned u; float f;} v; v.u=((unsigned)(unsigned short)s)<<16; return v.f;
}
__device__ __forceinline__ float exp2v(float x){
  float r; asm("v_exp_f32 %0, %1" : "=v"(r) : "v"(x)); return r;
}
__device__ __forceinline__ unsigned cvtpk(float lo, float hi){
  unsigned r; asm("v_cvt_pk_bf16_f32 %0, %1, %2" : "=v"(r) : "v"(lo), "v"(hi)); return r;
}

// ---------------- weights fp32 -> bf16 (Ww gets hi/lo split) ----------------
__global__ void k_cvt_w(const float* __restrict__ Wt, const float* __restrict__ Wp,
                        const float* __restrict__ Wg, const float* __restrict__ Ww,
                        short* __restrict__ out){
  int i = blockIdx.x*256 + threadIdx.x;   // 131072 total
  if (i < 98304){
    const float* src; int off;
    if (i < 32768)      { src = Wt; off = i; }
    else if (i < 65536) { src = Wp; off = i-32768; }
    else                { src = Wg; off = i-65536; }
    out[i] = f2bf(src[off]);
  } else {
    float v = Ww[i-98304];
    short hi = f2bf(v);
    out[i] = hi;                                  // Ww_hi at [98304,131072)
    out[i+32768] = f2bf(v - bf2f(hi));            // Ww_lo at [131072,163840)
  }
}

// ---------------- fused transpose + 3 projection convs ----------------
__global__ __launch_bounds__(256) void k_tconv(const float* __restrict__ x, const short* __restrict__ Wbf,
                        const float* __restrict__ bt, const float* __restrict__ bp, const float* __restrict__ bg,
                        short* __restrict__ theta, short* __restrict__ phiF, short* __restrict__ gF){
  __shared__ short xt[32*256];   // [pos][c], 16B-granule swizzle: g' = (c>>3) ^ (pos&7)
  int t = threadIdx.x;
  int wv = t >> 6, lane = t & 63;
  int l16 = lane & 15, lg = lane >> 4;
  int b = blockIdx.y, p0 = blockIdx.x*32;
  {
    const float* xr = x + ((size_t)b*NC + t)*NPOS + p0;
    union { float4 q[8]; float f[32]; } u;
    #pragma unroll
    for (int k=0;k<8;k++) u.q[k] = *(const float4*)(xr + k*4);
    int g0 = t >> 3, cb = t & 7;
    #pragma unroll
    for (int pos=0; pos<32; pos++)
      xt[pos*256 + ((g0 ^ (pos&7))<<3) + cb] = f2bf(u.f[pos]);
  }
  __syncthreads();
  bf16x8 a[2][8];
  #pragma unroll
  for (int ms=0;ms<2;ms++)
    #pragma unroll
    for (int ks=0;ks<8;ks++){
      int row = ms*16 + l16;
      a[ms][ks] = *(const bf16x8*)&xt[row*256 + (((ks*4+lg) ^ (row&7))<<3)];
    }
  int n0 = wv*32;
  for (int widx=0; widx<3; widx++){
    const short* Wb = Wbf + widx*32768;
    const float* bias = (widx==0) ? bt : ((widx==1) ? bp : bg);
    short* outp = (widx==0) ? theta : ((widx==1) ? phiF : gF);
    float osc = (widx==0) ? LOG2E : 1.0f;
    float bv[2];
    bv[0] = bias[n0+l16]; bv[1] = bias[n0+16+l16];
    f32x4 acc[2][2] = {};
    #pragma unroll
    for (int ks=0;ks<8;ks++)
      #pragma unroll
      for (int cs=0;cs<2;cs++){
        bf16x8 wf = *(const bf16x8*)&Wb[(n0+cs*16+l16)*NC + ks*32 + lg*8];
        acc[0][cs] = MFMA(a[0][ks], wf, acc[0][cs]);
        acc[1][cs] = MFMA(a[1][ks], wf, acc[1][cs]);
      }
    short* ob = outp + (size_t)b*NPOS*NCI;
    #pragma unroll
    for (int ms=0;ms<2;ms++)
      #pragma unroll
      for (int cs=0;cs<2;cs++)
        #pragma unroll
        for (int j=0;j<4;j++){
          int pos = p0 + ms*16 + lg*4 + j;
          int co  = n0 + cs*16 + l16;
          ob[(size_t)pos*NCI + co] = f2bf((acc[ms][cs][j] + bv[cs])*osc);
        }
  }
}

// ---------------- (1,2,2) max-pool: phiF(pos,128)->phiP(M,128); gF(pos,128)->gP(128,M) ----------------
__global__ void k_pool(const short* __restrict__ phiF, const short* __restrict__ gF,
                       short* __restrict__ phiP, short* __restrict__ gP){
  __shared__ short gb[128][17];
  int b = blockIdx.y, m0 = blockIdx.x*16;
  int lm = threadIdx.x >> 4, cg = threadIdx.x & 15, ci0 = cg*8;
  int m = m0 + lm;
  int tt = m/196, r = m%196, h2 = r/14, w2 = r%14;
  int pbase = tt*784 + h2*56 + w2*2;
  const short* pF  = phiF + (size_t)b*NPOS*NCI;
  const short* gFb = gF   + (size_t)b*NPOS*NCI;
  float pb[8], gv[8];
  #pragma unroll
  for (int i=0;i<8;i++){ pb[i]=-1e30f; gv[i]=-1e30f; }
  #pragma unroll
  for (int dh=0;dh<2;dh++)
    #pragma unroll
    for (int dw=0;dw<2;dw++){
      int pos = pbase + dh*28 + dw;
      bf16x8 v = *(const bf16x8*)&pF[(size_t)pos*NCI+ci0];
      bf16x8 g = *(const bf16x8*)&gFb[(size_t)pos*NCI+ci0];
      #pragma unroll
      for (int i=0;i<8;i++){ pb[i]=fmaxf(pb[i],bf2f(v[i])); gv[i]=fmaxf(gv[i],bf2f(g[i])); }
    }
  bf16x8 po;
  #pragma unroll
  for (int i=0;i<8;i++) po[i]=f2bf(pb[i]);
  *(bf16x8*)&phiP[(size_t)b*NM*NCI + (size_t)m*NCI + ci0] = po;
  #pragma unroll
  for (int i=0;i<8;i++) gb[ci0+i][lm] = f2bf(gv[i]);
  __syncthreads();
  if (threadIdx.x < 128){
    int row = threadIdx.x;
    bf16x8 a, c;
    #pragma unroll
    for (int j=0;j<8;j++){ a[j]=gb[row][j]; c[j]=gb[row][8+j]; }
    short* dst = gP + (size_t)b*NCI*NM + (size_t)row*NM + m0;
    *(bf16x8*)&dst[0] = a;
    *(bf16x8*)&dst[8] = c;
  }
}

// ---------------- flash attention v9: v5b loop + fused Ww GEMM epilogue ----------------
// writes wy (fp32, [b][ch][pos]) and per-(block,wave) channel sum/sumsq partials. No y hi/lo to memory.
__global__ __launch_bounds__(128,2) void k_attn(const short* __restrict__ theta, const short* __restrict__ phiP,
                       const short* __restrict__ gP, const short* __restrict__ Wwbf,
                       const float* __restrict__ bw, float* __restrict__ wy,
                       float* __restrict__ sum_part, float* __restrict__ sq_part){
  __shared__ __align__(16) char tiles[2][16384];        // loop: [buf][phi 8KB | g 8KB]; epilogue: per-wave yT hi/lo
  __shared__ __align__(16) unsigned pbs[2][2][320];
  int t = threadIdx.x;
  int wv = t >> 6, lane = t & 63;
  int l16 = lane & 15, lg = lane >> 4;
  int b = blockIdx.x & 7, qt = blockIdx.x >> 3;
  int q0 = qt*64 + wv*32;
  const short* th = theta + (size_t)b*NPOS*NCI;
  const char* gph = (const char*)(phiP + (size_t)b*NM*NCI);
  const char* gpg = (const char*)(gP   + (size_t)b*NCI*NM);

  int pr = (t >> 4) & 7, ps = t & 15;
  int gr = t >> 2, gs = t & 3;
  int lw_p[4], lw_g[4]; size_t go_p[4], go_g[4];
  #pragma unroll
  for (int k=0;k<4;k++){
    lw_p[k] = (pr+8*k)*256 + ((ps ^ pr) << 4);
    go_p[k] = (size_t)(pr+8*k)*256 + ps*16;
    lw_g[k] = 8192 + (gr+32*k)*64 + ((gs ^ (gr & 3)) << 4);
    go_g[k] = (size_t)(gr+32*k)*(NM*2) + gs*16;
  }
  int rp[2][4];
  #pragma unroll
  for (int mi=0;mi<2;mi++)
    #pragma unroll
    for (int kc=0;kc<4;kc++)
      rp[mi][kc] = (mi*16+l16)*256 + (((kc*4+lg) ^ (l16 & 7)) << 4);
  int rg[8];
  #pragma unroll
  for (int ct=0;ct<8;ct++)
    rg[ct] = 8192 + (ct*16+l16)*64 + ((lg ^ (l16 & 3)) << 4);

  int lgs01 = (2*lg) & 3, lgs23 = (2*lg+1) & 3;
  int mi2 = (lg >> 1) * 2;
  int rbase = l16*20;

  bf16x8 qf[2][4];
  #pragma unroll
  for (int qi=0;qi<2;qi++)
    #pragma unroll
    for (int kc=0;kc<4;kc++)
      qf[qi][kc] = *(const bf16x8*)&th[(size_t)(q0+qi*16+l16)*NCI + kc*32 + lg*8];
  f32x4 acc[2][8] = {};
  float lsum[2] = {0.f, 0.f};

  {
    uint4 A[8];
    #pragma unroll
    for (int k=0;k<4;k++){ A[k] = *(const uint4*)(gph + go_p[k]); A[4+k] = *(const uint4*)(gpg + go_g[k]); }
    #pragma unroll
    for (int k=0;k<4;k++){ *(uint4*)(tiles[0] + lw_p[k]) = A[k]; *(uint4*)(tiles[0] + lw_g[k]) = A[4+k]; }
  }
  __syncthreads();

  int cur = 0;
  for (int ms=0; ms<49; ms++){
    uint4 A[8];
    if (ms < 48){
      size_t pb_ = (size_t)(ms+1)*8192;
      size_t gb_ = (size_t)(ms+1)*64;
      #pragma unroll
      for (int k=0;k<4;k++){ A[k] = *(const uint4*)(gph + pb_ + go_p[k]); A[4+k] = *(const uint4*)(gpg + gb_ + go_g[k]); }
    }
    const char* L = tiles[cur];
    bf16x8 pf[2][4];
    #pragma unroll
    for (int mi=0;mi<2;mi++)
      #pragma unroll
      for (int kc=0;kc<4;kc++)
        pf[mi][kc] = *(const bf16x8*)(L + rp[mi][kc]);
    f32x4 s[2][2] = {};
    __builtin_amdgcn_s_setprio(1);
    #pragma unroll
    for (int qi=0;qi<2;qi++)
      #pragma unroll
      for (int mi=0;mi<2;mi++)
        #pragma unroll
        for (int kc=0;kc<4;kc++)
          s[qi][mi] = MFMA(pf[mi][kc], qf[qi][kc], s[qi][mi]);
    __builtin_amdgcn_s_setprio(0);
    bf16x8 gf[8];
    #pragma unroll
    for (int ct=0;ct<8;ct++)
      gf[ct] = *(const bf16x8*)(L + rg[ct]);
    #pragma unroll
    for (int qi=0;qi<2;qi++){
      float e0=exp2v(s[qi][0][0]), e1=exp2v(s[qi][0][1]), e2=exp2v(s[qi][0][2]), e3=exp2v(s[qi][0][3]);
      float e4=exp2v(s[qi][1][0]), e5=exp2v(s[qi][1][1]), e6=exp2v(s[qi][1][2]), e7=exp2v(s[qi][1][3]);
      lsum[qi] += (e0+e1)+(e2+e3)+(e4+e5)+(e6+e7);
      uint4 pk;
      pk.x = cvtpk(e0,e1); pk.y = cvtpk(e2,e3); pk.z = cvtpk(e4,e5); pk.w = cvtpk(e6,e7);
      *(uint4*)&pbs[wv][qi][rbase + lg*4] = pk;
    }
    union { unsigned u[4]; bf16x8 v; } pbv[2];
    #pragma unroll
    for (int qi=0;qi<2;qi++){
      pbv[qi].u[0] = pbs[wv][qi][rbase + lgs01*4 + mi2 + 0];
      pbv[qi].u[1] = pbs[wv][qi][rbase + lgs01*4 + mi2 + 1];
      pbv[qi].u[2] = pbs[wv][qi][rbase + lgs23*4 + mi2 + 0];
      pbv[qi].u[3] = pbs[wv][qi][rbase + lgs23*4 + mi2 + 1];
    }
    __builtin_amdgcn_s_setprio(1);
    #pragma unroll
    for (int ct=0;ct<8;ct++){
      acc[0][ct] = MFMA(gf[ct], pbv[0].v, acc[0][ct]);
      acc[1][ct] = MFMA(gf[ct], pbv[1].v, acc[1][ct]);
    }
    __builtin_amdgcn_s_setprio(0);
    if (ms < 48){
      char* D = tiles[cur^1];
      #pragma unroll
      for (int k=0;k<4;k++){ *(uint4*)(D + lw_p[k]) = A[k]; *(uint4*)(D + lw_g[k]) = A[4+k]; }
    }
    __syncthreads();
    cur ^= 1;
  }

  // ---- epilogue: normalize, hi/lo split into per-wave LDS as B-frag tiles [q][ci] ----
  float inv[2];
  #pragma unroll
  for (int qi=0;qi<2;qi++){
    float v = lsum[qi];
    v += __shfl_xor(v, 16); v += __shfl_xor(v, 32);
    inv[qi] = 1.f / v;
  }
  {
    char* Y = tiles[0] + wv*16384;          // 8KB hi | 8KB lo
    #pragma unroll
    for (int qi=0;qi<2;qi++){
      int q = qi*16 + l16;
      int rowoff = q*256 + ((lg&1)<<3);
      #pragma unroll
      for (int ct=0;ct<8;ct++){
        float v0 = acc[qi][ct][0]*inv[qi];
        float v1 = acc[qi][ct][1]*inv[qi];
        float v2 = acc[qi][ct][2]*inv[qi];
        float v3 = acc[qi][ct][3]*inv[qi];
        unsigned h0 = cvtpk(v0,v1), h1 = cvtpk(v2,v3);
        float l0 = v0 - bf2f((short)(h0 & 0xffff));
        float l1 = v1 - bf2f((short)(h0 >> 16));
        float l2 = v2 - bf2f((short)(h1 & 0xffff));
        float l3 = v3 - bf2f((short)(h1 >> 16));
        unsigned o0 = cvtpk(l0,l1), o1 = cvtpk(l2,l3);
        int g = ct*2 + (lg>>1);
        int off = rowoff + (((g ^ (q&7))) << 4);
        uint2 hv; hv.x = h0; hv.y = h1;
        uint2 lv; lv.x = o0; lv.y = o1;
        *(uint2*)(Y + off) = hv;
        *(uint2*)(Y + 8192 + off) = lv;
      }
    }
  }
  __syncthreads();
  // B-frags back from LDS
  bf16x8 bhi[2][4], blo[2][4];
  {
    const char* Y = tiles[0] + wv*16384;
    #pragma unroll
    for (int qi=0;qi<2;qi++)
      #pragma unroll
      for (int kc=0;kc<4;kc++){
        int off = (qi*16+l16)*256 + ((((kc*4+lg) ^ (l16&7))) << 4);
        bhi[qi][kc] = *(const bf16x8*)(Y + off);
        blo[qi][kc] = *(const bf16x8*)(Y + 8192 + off);
      }
  }
  // Ww GEMM (hi/lo) + wy store + per-channel partials
  const short* Whi = Wwbf;
  const short* Wlo = Wwbf + 32768;
  int slot = blockIdx.x*2 + wv;             // [0,1568)
  int posq = q0 + l16;                      // qi=0 position; qi=1 at +16
  for (int cht=0; cht<16; cht++){
    bf16x8 ahi[4], alo[4];
    #pragma unroll
    for (int kc=0;kc<4;kc++){
      ahi[kc] = *(const bf16x8*)&Whi[(cht*16+l16)*NCI + kc*32 + lg*8];
      alo[kc] = *(const bf16x8*)&Wlo[(cht*16+l16)*NCI + kc*32 + lg*8];
    }
    f32x4 e0 = {}, e1 = {};
    #pragma unroll
    for (int kc=0;kc<4;kc++){
      e0 = MFMA(ahi[kc], bhi[0][kc], e0);
      e0 = MFMA(ahi[kc], blo[0][kc], e0);
      e0 = MFMA(alo[kc], bhi[0][kc], e0);
      e1 = MFMA(ahi[kc], bhi[1][kc], e1);
      e1 = MFMA(ahi[kc], blo[1][kc], e1);
      e1 = MFMA(alo[kc], bhi[1][kc], e1);
    }
    #pragma unroll
    for (int j=0;j<4;j++){
      int ch = cht*16 + lg*4 + j;
      float bwv = bw[ch];
      float v0 = e0[j] + bwv, v1 = e1[j] + bwv;
      size_t base = ((size_t)b*NC + ch)*NPOS + posq;
      wy[base] = v0;
      wy[base + 16] = v1;
      float sv = v0 + v1, qv = v0*v0 + v1*v1;
      sv += __shfl_xor(sv,1); sv += __shfl_xor(sv,2); sv += __shfl_xor(sv,4); sv += __shfl_xor(sv,8);
      qv += __shfl_xor(qv,1); qv += __shfl_xor(qv,2); qv += __shfl_xor(qv,4); qv += __shfl_xor(qv,8);
      if (l16==0){
        sum_part[ch*1568 + slot] = sv;
        sq_part [ch*1568 + slot] = qv;
      }
    }
  }
}

__global__ void k_finstats(const float* __restrict__ sum_part, const float* __restrict__ sq_part,
                           const float* __restrict__ gamma, const float* __restrict__ beta,
                           float* __restrict__ scale, float* __restrict__ shift){
  __shared__ float r[4][2];
  int c = blockIdx.x;
  int t = threadIdx.x, wv = t>>6;
  float s=0.f, q=0.f;
  for (int k=t; k<1568; k+=256){ s += sum_part[c*1568+k]; q += sq_part[c*1568+k]; }
  #pragma unroll
  for (int off=1; off<64; off<<=1){ s += __shfl_xor(s,off); q += __shfl_xor(q,off); }
  if ((t&63)==0){ r[wv][0]=s; r[wv][1]=q; }
  __syncthreads();
  if (t==0){
    s = r[0][0]+r[1][0]+r[2][0]+r[3][0];
    q = r[0][1]+r[1][1]+r[2][1]+r[3][1];
    float mean = s*(1.f/PTOT);
    float var  = fmaxf(q*(1.f/PTOT) - mean*mean, 0.f);
    float rs = rsqrtf(var + 1e-5f);
    float sc = gamma[c]*rs;
    scale[c]=sc; shift[c]=beta[c]-mean*sc;
  }
}

// ---------------- elementwise: out = wy*scale + shift + x ----------------
__global__ __launch_bounds__(256) void k_out(const float* __restrict__ wy, const float* __restrict__ scale,
                      const float* __restrict__ shift, const float* __restrict__ x, float* __restrict__ out){
  int bid = blockIdx.x;                     // b*NC + ch
  int ch = bid & 255;
  float scv = scale[ch], shv = shift[ch];
  size_t base = (size_t)bid * NPOS;
  const float4* w4 = (const float4*)(wy + base);
  const float4* x4 = (const float4*)(x + base);
  float4* o4 = (float4*)(out + base);
  for (int k = threadIdx.x; k < NPOS/4; k += 256){
    float4 w = w4[k], xx = x4[k];
    float4 r;
    r.x = w.x*scv + shv + xx.x;
    r.y = w.y*scv + shv + xx.y;
    r.z = w.z*scv + shv + xx.z;
    r.w = w.w*scv + shv + xx.w;
    o4[k] = r;
  }
}

extern "C" void kernel_launch(void* const* d_in, const int* in_sizes, int n_in,
                              void* d_out, int out_size, void* d_ws, size_t ws_size,
                              hipStream_t stream){
  const float* x     = (const float*)d_in[0];
  const float* Wg    = (const float*)d_in[1];
  const float* bg    = (const float*)d_in[2];
  const float* Wt    = (const float*)d_in[3];
  const float* bt    = (const float*)d_in[4];
  const float* Wp    = (const float*)d_in[5];
  const float* bp    = (const float*)d_in[6];
  const float* Ww    = (const float*)d_in[7];
  const float* bw    = (const float*)d_in[8];
  const float* gamma = (const float*)d_in[9];
  const float* beta  = (const float*)d_in[10];
  float* out = (float*)d_out;

  char* w = (char*)d_ws;
  short* Wbf   = (short*)w;                           // 327,680 B (Wt,Wp,Wg,Ww_hi,Ww_lo)
  short* theta = (short*)(w + 327680);                // 12,845,056  (read by attn)
  short* phiP  = (short*)(w + 13172736);              //  3,211,264  (read by attn)
  short* gP    = (short*)(w + 16384000);              //  3,211,264  (read by attn)
  short* phiF  = (short*)(w + 19595264);              // 12,845,056  (dead after pool)
  short* gF    = (short*)(w + 32440320);              // 12,845,056  (dead after pool)
  float* wy    = (float*)(w + 19595264);              // 51,380,224  (overlaps phiF+gF+fresh; ends 70,975,488)
  float* sum_part = (float*)(w + 70975488);           //  1,605,632
  float* sq_part  = (float*)(w + 72581120);           //  1,605,632
  float* scale    = (float*)(w + 74186752);           //  1,024
  float* shift    = (float*)(w + 74187776);           //  1,024

  k_cvt_w<<<dim3(512),256,0,stream>>>(Wt,Wp,Wg,Ww,Wbf);
  k_tconv<<<dim3(196,8),256,0,stream>>>(x,Wbf,bt,bp,bg,theta,phiF,gF);
  k_pool<<<dim3(98,8),256,0,stream>>>(phiF,gF,phiP,gP);
  const short* Wwbf = Wbf + 98304;
  k_attn<<<dim3(784),128,0,stream>>>(theta,phiP,gP,Wwbf,bw,wy,sum_part,sq_part);
  k_finstats<<<dim3(256),256,0,stream>>>(sum_part,sq_part,gamma,beta,scale,shift);
  k_out<<<dim3(2048),256,0,stream>>>(wy,scale,shift,x,out);
}

// Round 12
// 189.761 us; speedup vs baseline: 1.4995x; 1.0434x over previous
//
#include <hip/hip_runtime.h>
#include <hip/hip_bf16.h>

#define NB 8
#define NC 256
#define NCI 128
#define NPOS 6272   // 8*28*28
#define NM 1568     // 8*14*14
#define PTOT 50176  // 8*6272
#define LOG2E 1.44269504f

typedef __attribute__((ext_vector_type(8))) short bf16x8;
typedef __attribute__((ext_vector_type(4))) float f32x4;
#define MFMA(a,b,c) __builtin_amdgcn_mfma_f32_16x16x32_bf16((a),(b),(c),0,0,0)

__device__ __forceinline__ short f2bf(float f){
  union{float f; unsigned u;} v; v.f=f;
  unsigned r=(v.u + 0x7FFFu + ((v.u>>16)&1u))>>16;
  return (short)r;
}
__device__ __forceinline__ float bf2f(short s){
  union{unsigned u; float f;} v; v.u=((unsigned)(unsigned short)s)<<16; return v.f;
}
__device__ __forceinline__ float exp2v(float x){
  float r; asm("v_exp_f32 %0, %1" : "=v"(r) : "v"(x)); return r;
}
__device__ __forceinline__ unsigned cvtpk(float lo, float hi){
  unsigned r; asm("v_cvt_pk_bf16_f32 %0, %1, %2" : "=v"(r) : "v"(lo), "v"(hi)); return r;
}

// ---------------- weights fp32 -> bf16 (Ww gets hi/lo split) ----------------
__global__ void k_cvt_w(const float* __restrict__ Wt, const float* __restrict__ Wp,
                        const float* __restrict__ Wg, const float* __restrict__ Ww,
                        short* __restrict__ out){
  int i = blockIdx.x*256 + threadIdx.x;   // 131072 total
  if (i < 98304){
    const float* src; int off;
    if (i < 32768)      { src = Wt; off = i; }
    else if (i < 65536) { src = Wp; off = i-32768; }
    else                { src = Wg; off = i-65536; }
    out[i] = f2bf(src[off]);
  } else {
    float v = Ww[i-98304];
    short hi = f2bf(v);
    out[i] = hi;                                  // Ww_hi at [98304,131072)
    out[i+32768] = f2bf(v - bf2f(hi));            // Ww_lo at [131072,163840)
  }
}

// ---------------- fused transpose + 3 projection convs ----------------
__global__ __launch_bounds__(256) void k_tconv(const float* __restrict__ x, const short* __restrict__ Wbf,
                        const float* __restrict__ bt, const float* __restrict__ bp, const float* __restrict__ bg,
                        short* __restrict__ theta, short* __restrict__ phiF, short* __restrict__ gF){
  __shared__ short xt[32*256];   // [pos][c], 16B-granule swizzle: g' = (c>>3) ^ (pos&7)
  int t = threadIdx.x;
  int wv = t >> 6, lane = t & 63;
  int l16 = lane & 15, lg = lane >> 4;
  int b = blockIdx.y, p0 = blockIdx.x*32;
  {
    const float* xr = x + ((size_t)b*NC + t)*NPOS + p0;
    union { float4 q[8]; float f[32]; } u;
    #pragma unroll
    for (int k=0;k<8;k++) u.q[k] = *(const float4*)(xr + k*4);
    int g0 = t >> 3, cb = t & 7;
    #pragma unroll
    for (int pos=0; pos<32; pos++)
      xt[pos*256 + ((g0 ^ (pos&7))<<3) + cb] = f2bf(u.f[pos]);
  }
  __syncthreads();
  bf16x8 a[2][8];
  #pragma unroll
  for (int ms=0;ms<2;ms++)
    #pragma unroll
    for (int ks=0;ks<8;ks++){
      int row = ms*16 + l16;
      a[ms][ks] = *(const bf16x8*)&xt[row*256 + (((ks*4+lg) ^ (row&7))<<3)];
    }
  int n0 = wv*32;
  for (int widx=0; widx<3; widx++){
    const short* Wb = Wbf + widx*32768;
    const float* bias = (widx==0) ? bt : ((widx==1) ? bp : bg);
    short* outp = (widx==0) ? theta : ((widx==1) ? phiF : gF);
    float osc = (widx==0) ? LOG2E : 1.0f;
    float bv[2];
    bv[0] = bias[n0+l16]; bv[1] = bias[n0+16+l16];
    f32x4 acc[2][2] = {};
    #pragma unroll
    for (int ks=0;ks<8;ks++)
      #pragma unroll
      for (int cs=0;cs<2;cs++){
        bf16x8 wf = *(const bf16x8*)&Wb[(n0+cs*16+l16)*NC + ks*32 + lg*8];
        acc[0][cs] = MFMA(a[0][ks], wf, acc[0][cs]);
        acc[1][cs] = MFMA(a[1][ks], wf, acc[1][cs]);
      }
    short* ob = outp + (size_t)b*NPOS*NCI;
    #pragma unroll
    for (int ms=0;ms<2;ms++)
      #pragma unroll
      for (int cs=0;cs<2;cs++)
        #pragma unroll
        for (int j=0;j<4;j++){
          int pos = p0 + ms*16 + lg*4 + j;
          int co  = n0 + cs*16 + l16;
          ob[(size_t)pos*NCI + co] = f2bf((acc[ms][cs][j] + bv[cs])*osc);
        }
  }
}

// ---------------- (1,2,2) max-pool: phiF(pos,128)->phiP(M,128); gF(pos,128)->gP(128,M) ----------------
__global__ void k_pool(const short* __restrict__ phiF, const short* __restrict__ gF,
                       short* __restrict__ phiP, short* __restrict__ gP){
  __shared__ short gb[128][17];
  int b = blockIdx.y, m0 = blockIdx.x*16;
  int lm = threadIdx.x >> 4, cg = threadIdx.x & 15, ci0 = cg*8;
  int m = m0 + lm;
  int tt = m/196, r = m%196, h2 = r/14, w2 = r%14;
  int pbase = tt*784 + h2*56 + w2*2;
  const short* pF  = phiF + (size_t)b*NPOS*NCI;
  const short* gFb = gF   + (size_t)b*NPOS*NCI;
  float pb[8], gv[8];
  #pragma unroll
  for (int i=0;i<8;i++){ pb[i]=-1e30f; gv[i]=-1e30f; }
  #pragma unroll
  for (int dh=0;dh<2;dh++)
    #pragma unroll
    for (int dw=0;dw<2;dw++){
      int pos = pbase + dh*28 + dw;
      bf16x8 v = *(const bf16x8*)&pF[(size_t)pos*NCI+ci0];
      bf16x8 g = *(const bf16x8*)&gFb[(size_t)pos*NCI+ci0];
      #pragma unroll
      for (int i=0;i<8;i++){ pb[i]=fmaxf(pb[i],bf2f(v[i])); gv[i]=fmaxf(gv[i],bf2f(g[i])); }
    }
  bf16x8 po;
  #pragma unroll
  for (int i=0;i<8;i++) po[i]=f2bf(pb[i]);
  *(bf16x8*)&phiP[(size_t)b*NM*NCI + (size_t)m*NCI + ci0] = po;
  #pragma unroll
  for (int i=0;i<8;i++) gb[ci0+i][lm] = f2bf(gv[i]);
  __syncthreads();
  if (threadIdx.x < 128){
    int row = threadIdx.x;
    bf16x8 a, c;
    #pragma unroll
    for (int j=0;j<8;j++){ a[j]=gb[row][j]; c[j]=gb[row][8+j]; }
    short* dst = gP + (size_t)b*NCI*NM + (size_t)row*NM + m0;
    *(bf16x8*)&dst[0] = a;
    *(bf16x8*)&dst[8] = c;
  }
}

// ---------------- flash attention v10: v5b loop + swapped-operand Ww GEMM epilogue ----------------
// epilogue MFMA(y_frag, W_frag): D row=pos, col=ch -> float4 wy stores + 4 shuffles/cht for stats.
__global__ __launch_bounds__(128,2) void k_attn(const short* __restrict__ theta, const short* __restrict__ phiP,
                       const short* __restrict__ gP, const short* __restrict__ Wwbf,
                       const float* __restrict__ bw, float* __restrict__ wy,
                       float* __restrict__ sum_part, float* __restrict__ sq_part){
  __shared__ __align__(16) char tiles[2][16384];        // loop: [buf][phi 8KB | g 8KB]; epilogue: per-wave yT hi/lo
  __shared__ __align__(16) unsigned pbs[2][2][320];
  int t = threadIdx.x;
  int wv = t >> 6, lane = t & 63;
  int l16 = lane & 15, lg = lane >> 4;
  int b = blockIdx.x & 7, qt = blockIdx.x >> 3;
  int q0 = qt*64 + wv*32;
  const short* th = theta + (size_t)b*NPOS*NCI;
  const char* gph = (const char*)(phiP + (size_t)b*NM*NCI);
  const char* gpg = (const char*)(gP   + (size_t)b*NCI*NM);

  int pr = (t >> 4) & 7, ps = t & 15;
  int gr = t >> 2, gs = t & 3;
  int lw_p[4], lw_g[4]; size_t go_p[4], go_g[4];
  #pragma unroll
  for (int k=0;k<4;k++){
    lw_p[k] = (pr+8*k)*256 + ((ps ^ pr) << 4);
    go_p[k] = (size_t)(pr+8*k)*256 + ps*16;
    lw_g[k] = 8192 + (gr+32*k)*64 + ((gs ^ (gr & 3)) << 4);
    go_g[k] = (size_t)(gr+32*k)*(NM*2) + gs*16;
  }
  int rp[2][4];
  #pragma unroll
  for (int mi=0;mi<2;mi++)
    #pragma unroll
    for (int kc=0;kc<4;kc++)
      rp[mi][kc] = (mi*16+l16)*256 + (((kc*4+lg) ^ (l16 & 7)) << 4);
  int rg[8];
  #pragma unroll
  for (int ct=0;ct<8;ct++)
    rg[ct] = 8192 + (ct*16+l16)*64 + ((lg ^ (l16 & 3)) << 4);

  int lgs01 = (2*lg) & 3, lgs23 = (2*lg+1) & 3;
  int mi2 = (lg >> 1) * 2;
  int rbase = l16*20;

  bf16x8 qf[2][4];
  #pragma unroll
  for (int qi=0;qi<2;qi++)
    #pragma unroll
    for (int kc=0;kc<4;kc++)
      qf[qi][kc] = *(const bf16x8*)&th[(size_t)(q0+qi*16+l16)*NCI + kc*32 + lg*8];
  f32x4 acc[2][8] = {};
  float lsum[2] = {0.f, 0.f};

  {
    uint4 A[8];
    #pragma unroll
    for (int k=0;k<4;k++){ A[k] = *(const uint4*)(gph + go_p[k]); A[4+k] = *(const uint4*)(gpg + go_g[k]); }
    #pragma unroll
    for (int k=0;k<4;k++){ *(uint4*)(tiles[0] + lw_p[k]) = A[k]; *(uint4*)(tiles[0] + lw_g[k]) = A[4+k]; }
  }
  __syncthreads();

  int cur = 0;
  for (int ms=0; ms<49; ms++){
    uint4 A[8];
    if (ms < 48){
      size_t pb_ = (size_t)(ms+1)*8192;
      size_t gb_ = (size_t)(ms+1)*64;
      #pragma unroll
      for (int k=0;k<4;k++){ A[k] = *(const uint4*)(gph + pb_ + go_p[k]); A[4+k] = *(const uint4*)(gpg + gb_ + go_g[k]); }
    }
    const char* L = tiles[cur];
    bf16x8 pf[2][4];
    #pragma unroll
    for (int mi=0;mi<2;mi++)
      #pragma unroll
      for (int kc=0;kc<4;kc++)
        pf[mi][kc] = *(const bf16x8*)(L + rp[mi][kc]);
    f32x4 s[2][2] = {};
    __builtin_amdgcn_s_setprio(1);
    #pragma unroll
    for (int qi=0;qi<2;qi++)
      #pragma unroll
      for (int mi=0;mi<2;mi++)
        #pragma unroll
        for (int kc=0;kc<4;kc++)
          s[qi][mi] = MFMA(pf[mi][kc], qf[qi][kc], s[qi][mi]);
    __builtin_amdgcn_s_setprio(0);
    bf16x8 gf[8];
    #pragma unroll
    for (int ct=0;ct<8;ct++)
      gf[ct] = *(const bf16x8*)(L + rg[ct]);
    #pragma unroll
    for (int qi=0;qi<2;qi++){
      float e0=exp2v(s[qi][0][0]), e1=exp2v(s[qi][0][1]), e2=exp2v(s[qi][0][2]), e3=exp2v(s[qi][0][3]);
      float e4=exp2v(s[qi][1][0]), e5=exp2v(s[qi][1][1]), e6=exp2v(s[qi][1][2]), e7=exp2v(s[qi][1][3]);
      lsum[qi] += (e0+e1)+(e2+e3)+(e4+e5)+(e6+e7);
      uint4 pk;
      pk.x = cvtpk(e0,e1); pk.y = cvtpk(e2,e3); pk.z = cvtpk(e4,e5); pk.w = cvtpk(e6,e7);
      *(uint4*)&pbs[wv][qi][rbase + lg*4] = pk;
    }
    union { unsigned u[4]; bf16x8 v; } pbv[2];
    #pragma unroll
    for (int qi=0;qi<2;qi++){
      pbv[qi].u[0] = pbs[wv][qi][rbase + lgs01*4 + mi2 + 0];
      pbv[qi].u[1] = pbs[wv][qi][rbase + lgs01*4 + mi2 + 1];
      pbv[qi].u[2] = pbs[wv][qi][rbase + lgs23*4 + mi2 + 0];
      pbv[qi].u[3] = pbs[wv][qi][rbase + lgs23*4 + mi2 + 1];
    }
    __builtin_amdgcn_s_setprio(1);
    #pragma unroll
    for (int ct=0;ct<8;ct++){
      acc[0][ct] = MFMA(gf[ct], pbv[0].v, acc[0][ct]);
      acc[1][ct] = MFMA(gf[ct], pbv[1].v, acc[1][ct]);
    }
    __builtin_amdgcn_s_setprio(0);
    if (ms < 48){
      char* D = tiles[cur^1];
      #pragma unroll
      for (int k=0;k<4;k++){ *(uint4*)(D + lw_p[k]) = A[k]; *(uint4*)(D + lw_g[k]) = A[4+k]; }
    }
    __syncthreads();
    cur ^= 1;
  }

  // ---- epilogue: normalize, hi/lo split into per-wave LDS as [q][ci] frag tiles ----
  float inv[2];
  #pragma unroll
  for (int qi=0;qi<2;qi++){
    float v = lsum[qi];
    v += __shfl_xor(v, 16); v += __shfl_xor(v, 32);
    inv[qi] = 1.f / v;
  }
  {
    char* Y = tiles[0] + wv*16384;          // 8KB hi | 8KB lo
    #pragma unroll
    for (int qi=0;qi<2;qi++){
      int q = qi*16 + l16;
      int rowoff = q*256 + ((lg&1)<<3);
      #pragma unroll
      for (int ct=0;ct<8;ct++){
        float v0 = acc[qi][ct][0]*inv[qi];
        float v1 = acc[qi][ct][1]*inv[qi];
        float v2 = acc[qi][ct][2]*inv[qi];
        float v3 = acc[qi][ct][3]*inv[qi];
        unsigned h0 = cvtpk(v0,v1), h1 = cvtpk(v2,v3);
        float l0 = v0 - bf2f((short)(h0 & 0xffff));
        float l1 = v1 - bf2f((short)(h0 >> 16));
        float l2 = v2 - bf2f((short)(h1 & 0xffff));
        float l3 = v3 - bf2f((short)(h1 >> 16));
        unsigned o0 = cvtpk(l0,l1), o1 = cvtpk(l2,l3);
        int g = ct*2 + (lg>>1);
        int off = rowoff + (((g ^ (q&7))) << 4);
        uint2 hv; hv.x = h0; hv.y = h1;
        uint2 lv; lv.x = o0; lv.y = o1;
        *(uint2*)(Y + off) = hv;
        *(uint2*)(Y + 8192 + off) = lv;
      }
    }
  }
  __syncthreads();
  // y frags back from LDS (A-operand: rows = q = l16, k = ci contiguous)
  bf16x8 bhi[2][4], blo[2][4];
  {
    const char* Y = tiles[0] + wv*16384;
    #pragma unroll
    for (int qi=0;qi<2;qi++)
      #pragma unroll
      for (int kc=0;kc<4;kc++){
        int off = (qi*16+l16)*256 + ((((kc*4+lg) ^ (l16&7))) << 4);
        bhi[qi][kc] = *(const bf16x8*)(Y + off);
        blo[qi][kc] = *(const bf16x8*)(Y + 8192 + off);
      }
  }
  // Ww GEMM (hi/lo), SWAPPED operands: D row = pos, col = ch -> float4 wy stores
  const short* Whi = Wwbf;
  const short* Wlo = Wwbf + 32768;
  int slot = blockIdx.x*2 + wv;             // [0,1568)
  for (int cht=0; cht<16; cht++){
    bf16x8 ahi[4], alo[4];
    #pragma unroll
    for (int kc=0;kc<4;kc++){
      ahi[kc] = *(const bf16x8*)&Whi[(cht*16+l16)*NCI + kc*32 + lg*8];
      alo[kc] = *(const bf16x8*)&Wlo[(cht*16+l16)*NCI + kc*32 + lg*8];
    }
    f32x4 e[2] = {};
    #pragma unroll
    for (int kc=0;kc<4;kc++){
      e[0] = MFMA(bhi[0][kc], ahi[kc], e[0]);
      e[0] = MFMA(blo[0][kc], ahi[kc], e[0]);
      e[0] = MFMA(bhi[0][kc], alo[kc], e[0]);
      e[1] = MFMA(bhi[1][kc], ahi[kc], e[1]);
      e[1] = MFMA(blo[1][kc], ahi[kc], e[1]);
      e[1] = MFMA(bhi[1][kc], alo[kc], e[1]);
    }
    int ch = cht*16 + l16;
    float bwv = bw[ch];
    float sv = 0.f, qv = 0.f;
    size_t chbase = ((size_t)b*NC + ch)*NPOS;
    #pragma unroll
    for (int qi=0;qi<2;qi++){
      float4 w4;
      float v0 = e[qi][0] + bwv, v1 = e[qi][1] + bwv, v2 = e[qi][2] + bwv, v3 = e[qi][3] + bwv;
      w4.x = v0; w4.y = v1; w4.z = v2; w4.w = v3;
      *(float4*)&wy[chbase + q0 + qi*16 + lg*4] = w4;
      sv += (v0+v1)+(v2+v3);
      qv += (v0*v0+v1*v1)+(v2*v2+v3*v3);
    }
    // reduce over lg groups (pos coverage 32) -> every lane has channel total
    sv += __shfl_xor(sv,16); sv += __shfl_xor(sv,32);
    qv += __shfl_xor(qv,16); qv += __shfl_xor(qv,32);
    if (lg==0){
      sum_part[ch*1568 + slot] = sv;
      sq_part [ch*1568 + slot] = qv;
    }
  }
}

__global__ void k_finstats(const float* __restrict__ sum_part, const float* __restrict__ sq_part,
                           const float* __restrict__ gamma, const float* __restrict__ beta,
                           float* __restrict__ scale, float* __restrict__ shift){
  __shared__ float r[4][2];
  int c = blockIdx.x;
  int t = threadIdx.x, wv = t>>6;
  float s=0.f, q=0.f;
  for (int k=t; k<1568; k+=256){ s += sum_part[c*1568+k]; q += sq_part[c*1568+k]; }
  #pragma unroll
  for (int off=1; off<64; off<<=1){ s += __shfl_xor(s,off); q += __shfl_xor(q,off); }
  if ((t&63)==0){ r[wv][0]=s; r[wv][1]=q; }
  __syncthreads();
  if (t==0){
    s = r[0][0]+r[1][0]+r[2][0]+r[3][0];
    q = r[0][1]+r[1][1]+r[2][1]+r[3][1];
    float mean = s*(1.f/PTOT);
    float var  = fmaxf(q*(1.f/PTOT) - mean*mean, 0.f);
    float rs = rsqrtf(var + 1e-5f);
    float sc = gamma[c]*rs;
    scale[c]=sc; shift[c]=beta[c]-mean*sc;
  }
}

// ---------------- elementwise: out = wy*scale + shift + x ----------------
__global__ __launch_bounds__(256) void k_out(const float* __restrict__ wy, const float* __restrict__ scale,
                      const float* __restrict__ shift, const float* __restrict__ x, float* __restrict__ out){
  int bid = blockIdx.x;                     // b*NC + ch
  int ch = bid & 255;
  float scv = scale[ch], shv = shift[ch];
  size_t base = (size_t)bid * NPOS;
  const float4* w4 = (const float4*)(wy + base);
  const float4* x4 = (const float4*)(x + base);
  float4* o4 = (float4*)(out + base);
  for (int k = threadIdx.x; k < NPOS/4; k += 256){
    float4 w = w4[k], xx = x4[k];
    float4 r;
    r.x = w.x*scv + shv + xx.x;
    r.y = w.y*scv + shv + xx.y;
    r.z = w.z*scv + shv + xx.z;
    r.w = w.w*scv + shv + xx.w;
    o4[k] = r;
  }
}

extern "C" void kernel_launch(void* const* d_in, const int* in_sizes, int n_in,
                              void* d_out, int out_size, void* d_ws, size_t ws_size,
                              hipStream_t stream){
  const float* x     = (const float*)d_in[0];
  const float* Wg    = (const float*)d_in[1];
  const float* bg    = (const float*)d_in[2];
  const float* Wt    = (const float*)d_in[3];
  const float* bt    = (const float*)d_in[4];
  const float* Wp    = (const float*)d_in[5];
  const float* bp    = (const float*)d_in[6];
  const float* Ww    = (const float*)d_in[7];
  const float* bw    = (const float*)d_in[8];
  const float* gamma = (const float*)d_in[9];
  const float* beta  = (const float*)d_in[10];
  float* out = (float*)d_out;

  char* w = (char*)d_ws;
  short* Wbf   = (short*)w;                           // 327,680 B (Wt,Wp,Wg,Ww_hi,Ww_lo)
  short* theta = (short*)(w + 327680);                // 12,845,056  (read by attn)
  short* phiP  = (short*)(w + 13172736);              //  3,211,264  (read by attn)
  short* gP    = (short*)(w + 16384000);              //  3,211,264  (read by attn)
  short* phiF  = (short*)(w + 19595264);              // 12,845,056  (dead after pool)
  short* gF    = (short*)(w + 32440320);              // 12,845,056  (dead after pool)
  float* wy    = (float*)(w + 19595264);              // 51,380,224  (overlaps phiF+gF+fresh)
  float* sum_part = (float*)(w + 70975488);           //  1,605,632
  float* sq_part  = (float*)(w + 72581120);           //  1,605,632
  float* scale    = (float*)(w + 74186752);           //  1,024
  float* shift    = (float*)(w + 74187776);           //  1,024

  k_cvt_w<<<dim3(512),256,0,stream>>>(Wt,Wp,Wg,Ww,Wbf);
  k_tconv<<<dim3(196,8),256,0,stream>>>(x,Wbf,bt,bp,bg,theta,phiF,gF);
  k_pool<<<dim3(98,8),256,0,stream>>>(phiF,gF,phiP,gP);
  const short* Wwbf = Wbf + 98304;
  k_attn<<<dim3(784),128,0,stream>>>(theta,phiP,gP,Wwbf,bw,wy,sum_part,sq_part);
  k_finstats<<<dim3(256),256,0,stream>>>(sum_part,sq_part,gamma,beta,scale,shift);
  k_out<<<dim3(2048),256,0,stream>>>(wy,scale,shift,x,out);
}